// Round 9
// baseline (442.651 us; speedup 1.0000x reference)
//
#include <hip/hip_runtime.h>

#define BS 2
#define NM 10
#define NA 8400
#define NC 80
#define NBIN 36
#define KTOP 13
#define NRECT (BS*NM*3)   // 60 rects: (bm, level)

// ---------------------------------------------------------------
// Closed-form in-box anchor rectangle for (bm, lv), endpoint-corrected
// with the exact float test the reference uses; membership is exact.
// ---------------------------------------------------------------
__device__ __forceinline__ void rect_one(int bm, int lv,
    const float* __restrict__ gtb, const float* __restrict__ mgt,
    int& x0, int& y0, int& cx, int& cnt, int& n, int& base){
  cnt = 0; x0 = 0; y0 = 0; cx = 0; n = 0; base = 0;
  if (mgt[bm] > 0.f){
    float s = (float)(8 << lv);
    n = 640 >> (3 + lv);                     // 80, 40, 20
    base = (lv == 0) ? 0 : ((lv == 1) ? 6400 : 8000);
    float lx = gtb[bm*4+0], ly = gtb[bm*4+1];
    float rx = gtb[bm*4+2], ry = gtb[bm*4+3];
    int a0 = (int)ceilf(lx/s - 0.5f); a0 = min(max(a0, 0), n);
    while (a0 > 0   &&  (((a0-1)+0.5f)*s - lx > 1e-9f)) a0--;
    while (a0 < n   && !(((a0  )+0.5f)*s - lx > 1e-9f)) a0++;
    int a1 = (int)floorf(rx/s - 0.5f); a1 = min(max(a1, -1), n-1);
    while (a1 < n-1 &&  (rx - ((a1+1)+0.5f)*s > 1e-9f)) a1++;
    while (a1 >= 0  && !(rx - ((a1  )+0.5f)*s > 1e-9f)) a1--;
    int b0 = (int)ceilf(ly/s - 0.5f); b0 = min(max(b0, 0), n);
    while (b0 > 0   &&  (((b0-1)+0.5f)*s - ly > 1e-9f)) b0--;
    while (b0 < n   && !(((b0  )+0.5f)*s - ly > 1e-9f)) b0++;
    int b1 = (int)floorf(ry/s - 0.5f); b1 = min(max(b1, -1), n-1);
    while (b1 < n-1 &&  (ry - ((b1+1)+0.5f)*s > 1e-9f)) b1++;
    while (b1 >= 0  && !(ry - ((b1  )+0.5f)*s > 1e-9f)) b1--;
    cx = max(0, a1 - a0 + 1);
    int cy = max(0, b1 - b0 + 1);
    cnt = cx * cy;
    x0 = a0; y0 = b0;
  }
}

__device__ __forceinline__ void rect_setup(int tid,
    const float* __restrict__ gtb, const float* __restrict__ mgt,
    int* sx0, int* sy0, int* scx, int* scum, int* sn, int* sbase){
  if (tid < NRECT){
    int bm = tid/3, lv = tid - bm*3;
    int x0, y0, cx, cnt, n, base;
    rect_one(bm, lv, gtb, mgt, x0, y0, cx, cnt, n, base);
    sx0[tid] = x0; sy0[tid] = y0; scx[tid] = cx;
    scum[tid] = cnt; sn[tid] = n; sbase[tid] = base;
  }
  __syncthreads();
  if (tid == 0){
    int acc = 0;
    for (int r = 0; r < NRECT; r++){ int c = scum[r]; scum[r] = acc; acc += c; }
    scum[NRECT] = acc;
  }
  __syncthreads();
}

__device__ __forceinline__ int pair_from_p(int p,
    const int* sx0, const int* sy0, const int* scx,
    const int* scum, const int* sn, const int* sbase){
  int r = 0;
  while (r < NRECT-1 && scum[r+1] <= p) r++;
  int idx = p - scum[r];
  int cx = scx[r];
  int yi = idx / cx;
  int xi = idx - yi*cx;
  int a = sbase[r] + (sy0[r] + yi)*sn[r] + (sx0[r] + xi);
  int bm = r/3;
  return bm*NA + a;
}

__device__ __forceinline__ bool in_pair(int t,
    const float* __restrict__ anc, const float* __restrict__ gtb,
    const float* __restrict__ mgt){
  int a = t % NA; int bm = t / NA;
  if (mgt[bm] <= 0.f) return false;
  float ax = anc[2*a], ay = anc[2*a+1];
  float lx = gtb[bm*4+0], ly = gtb[bm*4+1];
  float rx = gtb[bm*4+2], ry = gtb[bm*4+3];
  float mind = fminf(fminf(ax-lx, ay-ly), fminf(rx-ax, ry-ay));
  return (mind > 1e-9f);
}

// Scan one bucket's candidate list, maintaining lex-min-4 u64 keys
// key = (float_bits(diff) << 32) | point_index  -> order-independent exact
// reproduction of lax.top_k's (diff, index) tie rule.
__device__ __forceinline__ void scan_bucket(const float2* __restrict__ so,
    int st, int len, int kmax, float th,
    unsigned long long& k0, unsigned long long& k1,
    unsigned long long& k2, unsigned long long& k3){
  for (int k = 0; k < kmax; k++){
    bool pr = (k < len);
    float2 e = so[pr ? (st + k) : 0];
    float ad = fabsf(e.x - th);
    float diff = fminf(ad, 360.f - ad);
    unsigned long long key =
      ((unsigned long long)__float_as_uint(diff) << 32) |
      (unsigned int)__float_as_uint(e.y);
    if (pr && key < k3){
      k3 = key;
      if (k3 < k2){ unsigned long long tt=k2; k2=k3; k3=tt; }
      if (k2 < k1){ unsigned long long tt=k1; k1=k2; k2=tt; }
      if (k1 < k0){ unsigned long long tt=k0; k0=k1; k1=tt; }
    }
  }
}

// ---------------------------------------------------------------
// k_dist: fused zeroing + per-pair dist_max(36) + IoU + align.
// One WAVE per pair: stage 360 (dist,ang) -> LDS, counting-sort point
// indices into 36 angle buckets (2-pass LDS atomics, unordered within
// bucket -- lex keys make order irrelevant), then each of 36 lanes
// scans buckets +/-1 with exact expansion rule.
// ---------------------------------------------------------------
__global__ __launch_bounds__(256)
void k_dist(const float* __restrict__ pds, const float* __restrict__ pdb,
            const float* __restrict__ anc, const int* __restrict__ gl,
            const float* __restrict__ gtb, const float* __restrict__ mgt,
            const float* __restrict__ coor,
            float* __restrict__ out, float* __restrict__ wf){
  float* o_scores  = out + 84000;
  float* o_gtdist  = out + 1612800;
  float* o_cent    = out + 7660800;
  float* w_align = wf + 16;
  float* w_ovl   = w_align + BS*NM*NA;
  float* w_mask  = w_ovl + BS*NM*NA;
  float* w_pa    = w_mask + BS*NM*NA;   // + w_po contiguous (40 floats)

  __shared__ int sx0[NRECT], sy0[NRECT], scx[NRECT], scum[NRECT+1], sn[NRECT], sbase[NRECT];
  __shared__ float2 s_da[4][360];   // (dist, ang) by point index
  __shared__ float2 s_so[4][360];   // bucket-sorted (ang, idx_bits)
  __shared__ int s_cnt[4][NBIN];
  __shared__ int s_off[4][NBIN];
  __shared__ int s_pos[4][NBIN];

  int tid = threadIdx.x;
  int lane = tid & 63, wave = tid >> 6;
  int gsz  = gridDim.x * 256;
  int gtid = blockIdx.x * 256 + tid;

  rect_setup(tid, gtb, mgt, sx0, sy0, scx, scum, sn, sbase);
  int total = scum[NRECT];

  // ---- loop 1: zeroing (coalesced; disjoint from pair writes) ----
  {
    float4 z = make_float4(0.f, 0.f, 0.f, 0.f);
    float4* sc4 = (float4*)o_scores;
    for (int i = gtid; i < (BS*NA*NC)/4; i += gsz) sc4[i] = z;
    float4* ce4 = (float4*)o_cent;
    for (int i = gtid; i < (BS*NM*NA)/4; i += gsz) ce4[i] = z;
    if (gtid < 2*BS*NM) w_pa[gtid] = 0.f;
    for (int t = gtid; t < BS*NM*NA; t += gsz){
      w_mask[t] = 0.f;
      if (!in_pair(t, anc, gtb, mgt)){
        w_align[t] = 0.f;
        w_ovl[t]   = 0.f;
      }
    }
    float4* gd4 = (float4*)o_gtdist;
    for (int i = gtid; i < (BS*NM*NA*NBIN)/4; i += gsz){
      int t = i / 9;
      if (!in_pair(t, anc, gtb, mgt)) gd4[i] = z;
    }
  }

  // ---- loop 2: one wave per pair ----
  const unsigned long long KMAX = ~0ull;
  bool active = (lane < NBIN);
  int nwaves = gridDim.x * 4;
  for (int p = blockIdx.x*4 + wave; p < total; p += nwaves){
    int t = pair_from_p(p, sx0, sy0, scx, scum, sn, sbase);
    int a = t % NA; int bm = t / NA; int b = bm / NM;
    float ax = anc[2*a], ay = anc[2*a+1];
    const float* cc = coor + bm*720;

    if (active) s_cnt[wave][lane] = 0;
    __threadfence_block();

    // stage + count
    float angr[6]; int bktr[6];
#pragma unroll
    for (int c = 0; c < 6; c++){
      int i = lane + c*64;
      bktr[c] = -1;
      if (i < 360){
        float dx = cc[2*i]   - ax;
        float dy = cc[2*i+1] - ay;
        float dist = sqrtf(dx*dx + dy*dy);
        float an = atan2f(dy, dx) * 57.29577951308232f;
        if (an < 0.f) an += 360.f;
        s_da[wave][i] = make_float2(dist, an);
        int bkt = (int)(an*0.1f + 0.5f); if (bkt >= NBIN) bkt -= NBIN;
        angr[c] = an; bktr[c] = bkt;
        atomicAdd(&s_cnt[wave][bkt], 1);
      }
    }
    __threadfence_block();

    // exclusive prefix of cnt -> off, pos
    int myc = active ? s_cnt[wave][lane] : 0;
    int v = myc;
    for (int off = 1; off < 64; off <<= 1){
      int o = __shfl_up(v, off);
      if (lane >= off) v += o;
    }
    if (active){ s_off[wave][lane] = v - myc; s_pos[wave][lane] = v - myc; }
    // wave-max bucket count (uniform scan bound)
    int km = myc;
    for (int off = 32; off > 0; off >>= 1){
      int o = __shfl_xor(km, off);
      km = (o > km) ? o : km;
    }
    __threadfence_block();

    // scatter into bucket lists (unordered within bucket -- lex keys fix order)
#pragma unroll
    for (int c = 0; c < 6; c++){
      if (bktr[c] >= 0){
        int slot = atomicAdd(&s_pos[wave][bktr[c]], 1);
        s_so[wave][slot] = make_float2(angr[c], __int_as_float(lane + c*64));
      }
    }
    __threadfence_block();

    // windowed exact top-4 per bin
    unsigned long long k0 = KMAX, k1 = KMAX, k2 = KMAX, k3 = KMAX;
    float th = (float)(lane*10);
    for (int j = 0; j < 3; j++){
      int q = (lane + NBIN - 1 + j) % NBIN;
      int st = s_off[wave][q];
      int len = active ? s_cnt[wave][q] : 0;
      scan_bucket(&s_so[wave][0], st, len, km, th, k0, k1, k2, k3);
    }
    // expansion (rare): unscanned buckets at cyclic dist >= w have diff >= 10w-5
    if (active){
      int wext = 2;
      while (wext <= 18){
        float diff3 = __uint_as_float((unsigned int)(k3 >> 32));
        if (diff3 < (float)(10*wext - 5) - 0.01f) break;
        int qa = (lane + wext) % NBIN;
        int qb = (lane + NBIN - wext) % NBIN;
        scan_bucket(&s_so[wave][0], s_off[wave][qa], s_cnt[wave][qa],
                    s_cnt[wave][qa], th, k0, k1, k2, k3);
        if (qb != qa)
          scan_bucket(&s_so[wave][0], s_off[wave][qb], s_cnt[wave][qb],
                      s_cnt[wave][qb], th, k0, k1, k2, k3);
        wext++;
      }
    }

    // epilogue: dist_max, gt_dist write, IoU partials
    float sum_min = 0.f, sum_max = 0.f;
    if (active){
      float diff0 = __uint_as_float((unsigned int)(k0 >> 32));
      float dm;
      if (diff0 > 3.0f) dm = 1e-6f;
      else {
        int i0 = (int)(unsigned int)(k0 & 0xffffffffull);
        int i1 = (int)(unsigned int)(k1 & 0xffffffffull);
        int i2 = (int)(unsigned int)(k2 & 0xffffffffull);
        int i3 = (int)(unsigned int)(k3 & 0xffffffffull);
        dm = fmaxf(fmaxf(s_da[wave][i0].x, s_da[wave][i1].x),
                   fmaxf(s_da[wave][i2].x, s_da[wave][i3].x));
      }
      float dfin = fmaxf(dm, 1e-6f);
      o_gtdist[(size_t)t*NBIN + lane] = dfin;
      float pr = pdb[((size_t)b*NA + a)*NBIN + lane];
      sum_max = fmaxf(dfin, pr);
      sum_min = fmaxf(fminf(dfin, pr), 1e-6f);
    }
    for (int off = 32; off > 0; off >>= 1){
      sum_min += __shfl_down(sum_min, off);
      sum_max += __shfl_down(sum_max, off);
    }
    if (lane == 0){
      float ov = sum_min / sum_max;
      int cls = gl[bm];
      float sc = pds[((size_t)b*NA + a)*NC + cls];
      w_align[t] = sc * ov * ov * ov;
      w_ovl[t]   = ov;
    }
    __threadfence_block();
  }
}

// ---------------- top-13 per (b,m): rect-local candidates only --------------
__global__ __launch_bounds__(256)
void k_topk(const float* __restrict__ gtb, const float* __restrict__ mgt,
            const float* __restrict__ w_align, float* __restrict__ w_mask){
  int bm = blockIdx.x;
  const float* al = w_align + (size_t)bm*NA;
  int tid = threadIdx.x;
  __shared__ int rx0[3], ry0[3], rcx[3], rcum[4], rn[3], rbase[3];
  __shared__ float sv[256*KTOP];
  __shared__ int   si[256*KTOP];
  __shared__ float wv4[4];
  __shared__ int   wi4[4];

  if (tid < 3){
    int x0, y0, cx, cnt, n, base;
    rect_one(bm, tid, gtb, mgt, x0, y0, cx, cnt, n, base);
    rx0[tid]=x0; ry0[tid]=y0; rcx[tid]=cx; rcum[tid]=cnt; rn[tid]=n; rbase[tid]=base;
  }
  __syncthreads();
  if (tid == 0){
    int acc = 0;
#pragma unroll
    for (int r = 0; r < 3; r++){ int c = rcum[r]; rcum[r] = acc; acc += c; }
    rcum[3] = acc;
  }
  __syncthreads();
  int total = rcum[3];

  float v[KTOP]; int ix[KTOP];
#pragma unroll
  for (int j = 0; j < KTOP; j++){ v[j] = -1.f; ix[j] = 0x7fffffff; }
  for (int p = tid; p < total; p += 256){
    int r = (p >= rcum[1]) + (p >= rcum[2]);
    int idx = p - rcum[r];
    int cx = rcx[r];
    int yi = idx / cx;
    int xi = idx - yi*cx;
    int a = rbase[r] + (ry0[r] + yi)*rn[r] + (rx0[r] + xi);
    float x = al[a];
    if (x > v[KTOP-1]){
      v[KTOP-1] = x; ix[KTOP-1] = a;
#pragma unroll
      for (int j = KTOP-1; j > 0; j--){
        if (v[j] > v[j-1]){
          float tv = v[j-1]; v[j-1] = v[j]; v[j] = tv;
          int   ti = ix[j-1]; ix[j-1] = ix[j]; ix[j] = ti;
        }
      }
    }
  }
#pragma unroll
  for (int j = 0; j < KTOP; j++){ sv[tid*KTOP+j] = v[j]; si[tid*KTOP+j] = ix[j]; }

  int head = 0;
  int lane = tid & 63, wave = tid >> 6;
  for (int r = 0; r < KTOP; r++){
    float cv = sv[tid*KTOP + head];
    int   ci = si[tid*KTOP + head];
    float rv = cv; int ri = ci;
    for (int off = 32; off > 0; off >>= 1){
      float ov = __shfl_down(rv, off);
      int   oi = __shfl_down(ri, off);
      if (ov > rv || (ov == rv && oi < ri)){ rv = ov; ri = oi; }
    }
    if (lane == 0){ wv4[wave] = rv; wi4[wave] = ri; }
    __syncthreads();
    float Wv = wv4[0]; int Wi = wi4[0];
#pragma unroll
    for (int w = 1; w < 4; w++){
      float ov = wv4[w]; int oi = wi4[w];
      if (ov > Wv || (ov == Wv && oi < Wi)){ Wv = ov; Wi = oi; }
    }
    if (ci == Wi && head < KTOP-1) head++;
    if (tid == 0 && Wv > 0.f) w_mask[(size_t)bm*NA + Wi] = 1.f;
    __syncthreads();
  }
}

// ---------------- per-anchor finalize (+ fused pos_align/pos_ov atomics) ------
__global__ void k_final(const float* __restrict__ w_align, const float* __restrict__ w_ovl,
                        float* __restrict__ w_mask,
                        const int* __restrict__ gl, const float* __restrict__ gtb,
                        float* __restrict__ o_labels, float* __restrict__ o_bboxes,
                        float* __restrict__ o_maskpos, float* __restrict__ o_gtidx,
                        float* __restrict__ o_fg,
                        float* __restrict__ w_pa, float* __restrict__ w_po){
  int t = blockIdx.x*256 + threadIdx.x;
  if (t >= BS*NA) return;
  int a = t % NA, b = t / NA;
  float mp[NM];
  int fg = 0;
#pragma unroll
  for (int m = 0; m < NM; m++){
    mp[m] = w_mask[((size_t)(b*NM+m))*NA + a];
    fg += (mp[m] > 0.f) ? 1 : 0;
  }
  if (fg > 1){
    float bv = -1.f; int bi = 0;
#pragma unroll
    for (int m = 0; m < NM; m++){
      float v = w_ovl[((size_t)(b*NM+m))*NA + a];
      if (v > bv){ bv = v; bi = m; }
    }
#pragma unroll
    for (int m = 0; m < NM; m++){
      mp[m] = (m == bi) ? 1.f : 0.f;
      w_mask[((size_t)(b*NM+m))*NA + a] = mp[m];
    }
    fg = 1;
  }
  int tgt = 0;
#pragma unroll
  for (int m = NM-1; m >= 0; m--) if (mp[m] > 0.f) tgt = m;
#pragma unroll
  for (int m = 0; m < NM; m++) o_maskpos[((size_t)(b*NM+m))*NA + a] = mp[m];
  o_gtidx[t] = (float)tgt;
  o_fg[t] = (fg > 0) ? 1.f : 0.f;
  int lbl = gl[b*NM + tgt]; if (lbl < 0) lbl = 0;
  o_labels[t] = (float)lbl;
  const float* bx = gtb + (b*NM + tgt)*4;
  ((float4*)o_bboxes)[t] = make_float4(bx[0], bx[1], bx[2], bx[3]);
  if (fg > 0){
    int bmx = b*NM + tgt;
    float av  = w_align[(size_t)bmx*NA + a];
    float ovv = w_ovl[(size_t)bmx*NA + a];
    atomicMax((unsigned int*)&w_pa[bmx], __float_as_uint(av));
    atomicMax((unsigned int*)&w_po[bmx], __float_as_uint(ovv));
  }
}

// ---------------- fused tail: (A) gt_dist mask + centerness, (B) scores ------
#define NB_FIX 512
__global__ void k_fuse(const float* __restrict__ gtb, const float* __restrict__ mgt,
                       const float* __restrict__ w_mask, float* __restrict__ o_gtdist,
                       float* __restrict__ o_cent,
                       const float* __restrict__ w_align,
                       const float* __restrict__ w_pa, const float* __restrict__ w_po,
                       const float* __restrict__ o_labels, const float* __restrict__ o_fg,
                       const float* __restrict__ o_gtidx, float* __restrict__ o_scores){
  if (blockIdx.x < NB_FIX){
    __shared__ int sx0[NRECT], sy0[NRECT], scx[NRECT], scum[NRECT+1], sn[NRECT], sbase[NRECT];
    int tid = threadIdx.x;
    rect_setup(tid, gtb, mgt, sx0, sy0, scx, scum, sn, sbase);
    int total = scum[NRECT];
    int lane = tid & 63, wave = tid >> 6;
    for (int p = blockIdx.x*4 + wave; p < total; p += NB_FIX*4){
      int t = pair_from_p(p, sx0, sy0, scx, scum, sn, sbase);
      float m = w_mask[t];
      float* row = o_gtdist + (size_t)t*NBIN;
      if (m > 0.f){
        float vmin = 1e30f, vmax = 0.f;
        if (lane < NBIN){
          float v = row[lane];
          vmin = v; vmax = v;
        }
        for (int off = 32; off > 0; off >>= 1){
          vmin = fminf(vmin, __shfl_down(vmin, off));
          vmax = fmaxf(vmax, __shfl_down(vmax, off));
        }
        if (lane == 0) o_cent[t] = sqrtf(vmin / vmax);
      } else {
        if (lane < NBIN) row[lane] = 0.f;
      }
    }
  } else {
    int t = (blockIdx.x - NB_FIX)*256 + threadIdx.x;
    if (t < BS*NA && o_fg[t] > 0.f){
      int a = t % NA, b = t / NA;
      int m = (int)o_gtidx[t];
      int bm = b*NM + m;
      float av = w_align[(size_t)bm*NA + a];
      float norm = av * w_po[bm] / (w_pa[bm] + 1e-9f);
      int lbl = (int)o_labels[t];
      o_scores[(size_t)t*NC + lbl] = norm;
    }
  }
}

extern "C" void kernel_launch(void* const* d_in, const int* in_sizes, int n_in,
                              void* d_out, int out_size, void* d_ws, size_t ws_size,
                              hipStream_t stream){
  const float* pds  = (const float*)d_in[0]; // (2,8400,80)
  const float* pdb  = (const float*)d_in[1]; // (2,8400,36)
  const float* anc  = (const float*)d_in[2]; // (8400,2)
  const int*   gl   = (const int*)  d_in[3]; // (2,10,1)
  const float* gtb  = (const float*)d_in[4]; // (2,10,4)
  const float* mgt  = (const float*)d_in[5]; // (2,10,1)
  const float* coor = (const float*)d_in[6]; // (2,10,720)

  float* out = (float*)d_out;
  float* o_labels  = out;                                 // 16800
  float* o_bboxes  = o_labels + BS*NA;                    // 67200
  float* o_scores  = o_bboxes + BS*NA*4;                  // 1344000
  float* o_maskpos = o_scores + (size_t)BS*NA*NC;         // 168000
  float* o_gtidx   = o_maskpos + BS*NM*NA;                // 16800
  float* o_gtdist  = o_gtidx + BS*NA;                     // 6048000
  float* o_cent    = o_gtdist + (size_t)BS*NM*NA*NBIN;    // 168000
  float* o_fg      = o_cent + BS*NM*NA;                   // 16800

  float* wf      = (float*)d_ws;
  float* w_align = wf + 16;
  float* w_ovl   = w_align + BS*NM*NA;
  float* w_mask  = w_ovl + BS*NM*NA;
  float* w_pa    = w_mask + BS*NM*NA;
  float* w_po    = w_pa + BS*NM;

  k_dist<<<2048, 256, 0, stream>>>(pds, pdb, anc, gl, gtb, mgt, coor, out, wf);
  k_topk<<<BS*NM, 256, 0, stream>>>(gtb, mgt, w_align, w_mask);
  k_final<<<(BS*NA+255)/256, 256, 0, stream>>>(w_align, w_ovl, w_mask, gl, gtb,
                                               o_labels, o_bboxes, o_maskpos, o_gtidx, o_fg,
                                               w_pa, w_po);
  k_fuse<<<NB_FIX + (BS*NA+255)/256, 256, 0, stream>>>(gtb, mgt, w_mask,
                                                       o_gtdist, o_cent,
                                                       w_align, w_pa, w_po,
                                                       o_labels, o_fg, o_gtidx, o_scores);
}

// Round 10
// 169.714 us; speedup vs baseline: 2.6082x; 2.6082x over previous
//
#include <hip/hip_runtime.h>

#define BS 2
#define NM 10
#define NA 8400
#define NC 80
#define NBIN 36
#define KTOP 13
#define NRECT (BS*NM*3)   // 60 rects: (bm, level)

// ---------------------------------------------------------------
// Closed-form in-box anchor rectangle for (bm, lv), endpoint-corrected
// with the exact float test the reference uses; membership is exact.
// ---------------------------------------------------------------
__device__ __forceinline__ void rect_one(int bm, int lv,
    const float* __restrict__ gtb, const float* __restrict__ mgt,
    int& x0, int& y0, int& cx, int& cnt, int& n, int& base){
  cnt = 0; x0 = 0; y0 = 0; cx = 0; n = 0; base = 0;
  if (mgt[bm] > 0.f){
    float s = (float)(8 << lv);
    n = 640 >> (3 + lv);                     // 80, 40, 20
    base = (lv == 0) ? 0 : ((lv == 1) ? 6400 : 8000);
    float lx = gtb[bm*4+0], ly = gtb[bm*4+1];
    float rx = gtb[bm*4+2], ry = gtb[bm*4+3];
    int a0 = (int)ceilf(lx/s - 0.5f); a0 = min(max(a0, 0), n);
    while (a0 > 0   &&  (((a0-1)+0.5f)*s - lx > 1e-9f)) a0--;
    while (a0 < n   && !(((a0  )+0.5f)*s - lx > 1e-9f)) a0++;
    int a1 = (int)floorf(rx/s - 0.5f); a1 = min(max(a1, -1), n-1);
    while (a1 < n-1 &&  (rx - ((a1+1)+0.5f)*s > 1e-9f)) a1++;
    while (a1 >= 0  && !(rx - ((a1  )+0.5f)*s > 1e-9f)) a1--;
    int b0 = (int)ceilf(ly/s - 0.5f); b0 = min(max(b0, 0), n);
    while (b0 > 0   &&  (((b0-1)+0.5f)*s - ly > 1e-9f)) b0--;
    while (b0 < n   && !(((b0  )+0.5f)*s - ly > 1e-9f)) b0++;
    int b1 = (int)floorf(ry/s - 0.5f); b1 = min(max(b1, -1), n-1);
    while (b1 < n-1 &&  (ry - ((b1+1)+0.5f)*s > 1e-9f)) b1++;
    while (b1 >= 0  && !(ry - ((b1  )+0.5f)*s > 1e-9f)) b1--;
    cx = max(0, a1 - a0 + 1);
    int cy = max(0, b1 - b0 + 1);
    cnt = cx * cy;
    x0 = a0; y0 = b0;
  }
}

__device__ __forceinline__ void rect_setup(int tid,
    const float* __restrict__ gtb, const float* __restrict__ mgt,
    int* sx0, int* sy0, int* scx, int* scum, int* sn, int* sbase){
  if (tid < NRECT){
    int bm = tid/3, lv = tid - bm*3;
    int x0, y0, cx, cnt, n, base;
    rect_one(bm, lv, gtb, mgt, x0, y0, cx, cnt, n, base);
    sx0[tid] = x0; sy0[tid] = y0; scx[tid] = cx;
    scum[tid] = cnt; sn[tid] = n; sbase[tid] = base;
  }
  __syncthreads();
  if (tid == 0){
    int acc = 0;
    for (int r = 0; r < NRECT; r++){ int c = scum[r]; scum[r] = acc; acc += c; }
    scum[NRECT] = acc;
  }
  __syncthreads();
}

__device__ __forceinline__ int pair_from_p(int p,
    const int* sx0, const int* sy0, const int* scx,
    const int* scum, const int* sn, const int* sbase){
  int r = 0;
  while (r < NRECT-1 && scum[r+1] <= p) r++;
  int idx = p - scum[r];
  int cx = scx[r];
  int yi = idx / cx;
  int xi = idx - yi*cx;
  int a = sbase[r] + (sy0[r] + yi)*sn[r] + (sx0[r] + xi);
  int bm = r/3;
  return bm*NA + a;
}

// ---------------- k_zero: coalesced zero of out regions + ws -----------------
__global__ void k_zero(float* __restrict__ out, float* __restrict__ wf){
  float4 z = make_float4(0.f,0.f,0.f,0.f);
  int gsz = gridDim.x*256, gtid = blockIdx.x*256 + threadIdx.x;
  // o_scores
  float4* a = (float4*)(out + 84000);
  for (int i = gtid; i < 1344000/4; i += gsz) a[i] = z;
  // o_gtdist + o_cent (contiguous)
  float4* b = (float4*)(out + 1612800);
  for (int i = gtid; i < (6048000+168000)/4; i += gsz) b[i] = z;
  // ws: w_align, w_ovl, w_mask, w_pa, w_po
  float4* c = (float4*)(wf + 16);
  for (int i = gtid; i < (3*BS*NM*NA + 40)/4; i += gsz) c[i] = z;
}

// ---------------------------------------------------------------
// k_dist: one pair per block (4 waves). Stage 360 (dist,ang)->LDS,
// then flat lane-task scan: task id = wave*64+lane (0..215) maps to
// (bin = id%36, chunk = id/36), each scans 60 points with the uniform
// broadcast pattern and a stable top-4 insert network. Wave 0 then does
// a 6-way stable merge per bin (strict < prefers lower chunk = lower
// point index -> lax.top_k tie semantics preserved exactly).
// ---------------------------------------------------------------
__global__ __launch_bounds__(256)
void k_dist(const float* __restrict__ pds, const float* __restrict__ pdb,
            const float* __restrict__ anc, const int* __restrict__ gl,
            const float* __restrict__ gtb, const float* __restrict__ mgt,
            const float* __restrict__ coor,
            float* __restrict__ out, float* __restrict__ wf){
  float* o_gtdist  = out + 1612800;
  float* w_align = wf + 16;
  float* w_ovl   = w_align + BS*NM*NA;

  __shared__ int sx0[NRECT], sy0[NRECT], scx[NRECT], scum[NRECT+1], sn[NRECT], sbase[NRECT];
  __shared__ float2 s_da[360];        // (dist, ang)
  __shared__ float  s_m[NBIN*49];     // per bin: chunk c at [c*8+j], j<4 diff j>=4 dist (stride 49)

  int tid = threadIdx.x;
  int lane = tid & 63, wave = tid >> 6;

  rect_setup(tid, gtb, mgt, sx0, sy0, scx, scum, sn, sbase);
  int total = scum[NRECT];

  int id = tid;                 // 0..255
  int bin = id % 36;
  int chunk = id / 36;          // 0..7; active when < 6
  bool act = (id < 216);
  float th = (float)(bin*10);

  for (int p = blockIdx.x; p < total; p += gridDim.x){
    int t = pair_from_p(p, sx0, sy0, scx, scum, sn, sbase);
    int a = t % NA; int bm = t / NA; int b = bm / NM;
    float ax = anc[2*a], ay = anc[2*a+1];
    const float* cc = coor + bm*720;
    for (int i = tid; i < 360; i += 256){
      float dx = cc[2*i]   - ax;
      float dy = cc[2*i+1] - ay;
      float dist = sqrtf(dx*dx + dy*dy);
      float an = atan2f(dy, dx) * 57.29577951308232f;
      if (an < 0.f) an += 360.f;
      s_da[i] = make_float2(dist, an);
    }
    __syncthreads();
    if (act){
      float v0=1e30f, v1=1e30f, v2=1e30f, v3=1e30f;
      float d0=0.f, d1=0.f, d2=0.f, d3=0.f;
      int base = chunk*60;
      for (int k = 0; k < 60; k++){
        float2 da = s_da[base + k];
        float diff = fabsf(da.y - th);
        diff = fminf(diff, 360.f - diff);
        if (diff < v3){
          v3 = diff; d3 = da.x;
          if (v3 < v2){ float tv=v2; v2=v3; v3=tv; float td=d2; d2=d3; d3=td; }
          if (v2 < v1){ float tv=v1; v1=v2; v2=tv; float td=d1; d1=d2; d2=td; }
          if (v1 < v0){ float tv=v0; v0=v1; v1=tv; float td=d0; d0=d1; d1=td; }
        }
      }
      int mb = bin*49 + chunk*8;
      s_m[mb+0]=v0; s_m[mb+1]=v1; s_m[mb+2]=v2; s_m[mb+3]=v3;
      s_m[mb+4]=d0; s_m[mb+5]=d1; s_m[mb+6]=d2; s_m[mb+7]=d3;
    }
    __syncthreads();
    if (wave == 0){
      float sum_min = 0.f, sum_max = 0.f;
      if (lane < NBIN){
        int mb = lane*49;
        float h0=s_m[mb+0], h1=s_m[mb+8],  h2=s_m[mb+16],
              h3=s_m[mb+24], h4=s_m[mb+32], h5=s_m[mb+40];
        int p0=0, p1=0, p2=0, p3=0, p4=0, p5=0;
        float v0m = 0.f, dmax = 0.f;
#pragma unroll
        for (int step = 0; step < 4; step++){
          float bv = h0; int bw = 0;
          if (h1 < bv){ bv = h1; bw = 1; }
          if (h2 < bv){ bv = h2; bw = 2; }
          if (h3 < bv){ bv = h3; bw = 3; }
          if (h4 < bv){ bv = h4; bw = 4; }
          if (h5 < bv){ bv = h5; bw = 5; }
          float dd;
          if (bw == 0){ dd = s_m[mb+ 4+p0]; p0++; h0 = (p0<4)? s_m[mb   +p0] : 1e30f; }
          else if (bw == 1){ dd = s_m[mb+12+p1]; p1++; h1 = (p1<4)? s_m[mb+ 8+p1] : 1e30f; }
          else if (bw == 2){ dd = s_m[mb+20+p2]; p2++; h2 = (p2<4)? s_m[mb+16+p2] : 1e30f; }
          else if (bw == 3){ dd = s_m[mb+28+p3]; p3++; h3 = (p3<4)? s_m[mb+24+p3] : 1e30f; }
          else if (bw == 4){ dd = s_m[mb+36+p4]; p4++; h4 = (p4<4)? s_m[mb+32+p4] : 1e30f; }
          else             { dd = s_m[mb+44+p5]; p5++; h5 = (p5<4)? s_m[mb+40+p5] : 1e30f; }
          if (step == 0) v0m = bv;
          dmax = fmaxf(dmax, dd);
        }
        float dm = (v0m > 3.0f) ? 1e-6f : dmax;
        float dfin = fmaxf(dm, 1e-6f);
        o_gtdist[(size_t)t*NBIN + lane] = dfin;
        float pr = pdb[((size_t)b*NA + a)*NBIN + lane];
        sum_max = fmaxf(dfin, pr);
        sum_min = fmaxf(fminf(dfin, pr), 1e-6f);
      }
      for (int off = 32; off > 0; off >>= 1){
        sum_min += __shfl_down(sum_min, off);
        sum_max += __shfl_down(sum_max, off);
      }
      if (lane == 0){
        float ov = sum_min / sum_max;
        int cls = gl[bm];
        float sc = pds[((size_t)b*NA + a)*NC + cls];
        w_align[t] = sc * ov * ov * ov;
        w_ovl[t]   = ov;
      }
    }
    __syncthreads();
  }
}

// ---------------- top-13 per (b,m): rect-local candidates only --------------
__global__ __launch_bounds__(256)
void k_topk(const float* __restrict__ gtb, const float* __restrict__ mgt,
            const float* __restrict__ w_align, float* __restrict__ w_mask){
  int bm = blockIdx.x;
  const float* al = w_align + (size_t)bm*NA;
  int tid = threadIdx.x;
  __shared__ int rx0[3], ry0[3], rcx[3], rcum[4], rn[3], rbase[3];
  __shared__ float sv[256*KTOP];
  __shared__ int   si[256*KTOP];
  __shared__ float wv4[4];
  __shared__ int   wi4[4];

  if (tid < 3){
    int x0, y0, cx, cnt, n, base;
    rect_one(bm, tid, gtb, mgt, x0, y0, cx, cnt, n, base);
    rx0[tid]=x0; ry0[tid]=y0; rcx[tid]=cx; rcum[tid]=cnt; rn[tid]=n; rbase[tid]=base;
  }
  __syncthreads();
  if (tid == 0){
    int acc = 0;
#pragma unroll
    for (int r = 0; r < 3; r++){ int c = rcum[r]; rcum[r] = acc; acc += c; }
    rcum[3] = acc;
  }
  __syncthreads();
  int total = rcum[3];

  float v[KTOP]; int ix[KTOP];
#pragma unroll
  for (int j = 0; j < KTOP; j++){ v[j] = -1.f; ix[j] = 0x7fffffff; }
  for (int p = tid; p < total; p += 256){
    int r = (p >= rcum[1]) + (p >= rcum[2]);
    int idx = p - rcum[r];
    int cx = rcx[r];
    int yi = idx / cx;
    int xi = idx - yi*cx;
    int a = rbase[r] + (ry0[r] + yi)*rn[r] + (rx0[r] + xi);
    float x = al[a];
    if (x > v[KTOP-1]){
      v[KTOP-1] = x; ix[KTOP-1] = a;
#pragma unroll
      for (int j = KTOP-1; j > 0; j--){
        if (v[j] > v[j-1]){
          float tv = v[j-1]; v[j-1] = v[j]; v[j] = tv;
          int   ti = ix[j-1]; ix[j-1] = ix[j]; ix[j] = ti;
        }
      }
    }
  }
#pragma unroll
  for (int j = 0; j < KTOP; j++){ sv[tid*KTOP+j] = v[j]; si[tid*KTOP+j] = ix[j]; }

  int head = 0;
  int lane = tid & 63, wave = tid >> 6;
  for (int r = 0; r < KTOP; r++){
    float cv = sv[tid*KTOP + head];
    int   ci = si[tid*KTOP + head];
    float rv = cv; int ri = ci;
    for (int off = 32; off > 0; off >>= 1){
      float ov = __shfl_down(rv, off);
      int   oi = __shfl_down(ri, off);
      if (ov > rv || (ov == rv && oi < ri)){ rv = ov; ri = oi; }
    }
    if (lane == 0){ wv4[wave] = rv; wi4[wave] = ri; }
    __syncthreads();
    float Wv = wv4[0]; int Wi = wi4[0];
#pragma unroll
    for (int w = 1; w < 4; w++){
      float ov = wv4[w]; int oi = wi4[w];
      if (ov > Wv || (ov == Wv && oi < Wi)){ Wv = ov; Wi = oi; }
    }
    if (ci == Wi && head < KTOP-1) head++;
    if (tid == 0 && Wv > 0.f) w_mask[(size_t)bm*NA + Wi] = 1.f;
    __syncthreads();
  }
}

// ---------------- per-anchor finalize (+ fused pos_align/pos_ov atomics) ------
__global__ void k_final(const float* __restrict__ w_align, const float* __restrict__ w_ovl,
                        float* __restrict__ w_mask,
                        const int* __restrict__ gl, const float* __restrict__ gtb,
                        float* __restrict__ o_labels, float* __restrict__ o_bboxes,
                        float* __restrict__ o_maskpos, float* __restrict__ o_gtidx,
                        float* __restrict__ o_fg,
                        float* __restrict__ w_pa, float* __restrict__ w_po){
  int t = blockIdx.x*256 + threadIdx.x;
  if (t >= BS*NA) return;
  int a = t % NA, b = t / NA;
  float mp[NM];
  int fg = 0;
#pragma unroll
  for (int m = 0; m < NM; m++){
    mp[m] = w_mask[((size_t)(b*NM+m))*NA + a];
    fg += (mp[m] > 0.f) ? 1 : 0;
  }
  if (fg > 1){
    float bv = -1.f; int bi = 0;
#pragma unroll
    for (int m = 0; m < NM; m++){
      float v = w_ovl[((size_t)(b*NM+m))*NA + a];
      if (v > bv){ bv = v; bi = m; }
    }
#pragma unroll
    for (int m = 0; m < NM; m++){
      mp[m] = (m == bi) ? 1.f : 0.f;
      w_mask[((size_t)(b*NM+m))*NA + a] = mp[m];
    }
    fg = 1;
  }
  int tgt = 0;
#pragma unroll
  for (int m = NM-1; m >= 0; m--) if (mp[m] > 0.f) tgt = m;
#pragma unroll
  for (int m = 0; m < NM; m++) o_maskpos[((size_t)(b*NM+m))*NA + a] = mp[m];
  o_gtidx[t] = (float)tgt;
  o_fg[t] = (fg > 0) ? 1.f : 0.f;
  int lbl = gl[b*NM + tgt]; if (lbl < 0) lbl = 0;
  o_labels[t] = (float)lbl;
  const float* bx = gtb + (b*NM + tgt)*4;
  ((float4*)o_bboxes)[t] = make_float4(bx[0], bx[1], bx[2], bx[3]);
  if (fg > 0){
    int bmx = b*NM + tgt;
    float av  = w_align[(size_t)bmx*NA + a];
    float ovv = w_ovl[(size_t)bmx*NA + a];
    atomicMax((unsigned int*)&w_pa[bmx], __float_as_uint(av));
    atomicMax((unsigned int*)&w_po[bmx], __float_as_uint(ovv));
  }
}

// ---------------- fused tail: (A) gt_dist mask + centerness, (B) scores ------
#define NB_FIX 512
__global__ void k_fuse(const float* __restrict__ gtb, const float* __restrict__ mgt,
                       const float* __restrict__ w_mask, float* __restrict__ o_gtdist,
                       float* __restrict__ o_cent,
                       const float* __restrict__ w_align,
                       const float* __restrict__ w_pa, const float* __restrict__ w_po,
                       const float* __restrict__ o_labels, const float* __restrict__ o_fg,
                       const float* __restrict__ o_gtidx, float* __restrict__ o_scores){
  if (blockIdx.x < NB_FIX){
    __shared__ int sx0[NRECT], sy0[NRECT], scx[NRECT], scum[NRECT+1], sn[NRECT], sbase[NRECT];
    int tid = threadIdx.x;
    rect_setup(tid, gtb, mgt, sx0, sy0, scx, scum, sn, sbase);
    int total = scum[NRECT];
    int lane = tid & 63, wave = tid >> 6;
    for (int p = blockIdx.x*4 + wave; p < total; p += NB_FIX*4){
      int t = pair_from_p(p, sx0, sy0, scx, scum, sn, sbase);
      float m = w_mask[t];
      float* row = o_gtdist + (size_t)t*NBIN;
      if (m > 0.f){
        float vmin = 1e30f, vmax = 0.f;
        if (lane < NBIN){
          float v = row[lane];
          vmin = v; vmax = v;
        }
        for (int off = 32; off > 0; off >>= 1){
          vmin = fminf(vmin, __shfl_down(vmin, off));
          vmax = fmaxf(vmax, __shfl_down(vmax, off));
        }
        if (lane == 0) o_cent[t] = sqrtf(vmin / vmax);
      } else {
        if (lane < NBIN) row[lane] = 0.f;
      }
    }
  } else {
    int t = (blockIdx.x - NB_FIX)*256 + threadIdx.x;
    if (t < BS*NA && o_fg[t] > 0.f){
      int a = t % NA, b = t / NA;
      int m = (int)o_gtidx[t];
      int bm = b*NM + m;
      float av = w_align[(size_t)bm*NA + a];
      float norm = av * w_po[bm] / (w_pa[bm] + 1e-9f);
      int lbl = (int)o_labels[t];
      o_scores[(size_t)t*NC + lbl] = norm;
    }
  }
}

extern "C" void kernel_launch(void* const* d_in, const int* in_sizes, int n_in,
                              void* d_out, int out_size, void* d_ws, size_t ws_size,
                              hipStream_t stream){
  const float* pds  = (const float*)d_in[0]; // (2,8400,80)
  const float* pdb  = (const float*)d_in[1]; // (2,8400,36)
  const float* anc  = (const float*)d_in[2]; // (8400,2)
  const int*   gl   = (const int*)  d_in[3]; // (2,10,1)
  const float* gtb  = (const float*)d_in[4]; // (2,10,4)
  const float* mgt  = (const float*)d_in[5]; // (2,10,1)
  const float* coor = (const float*)d_in[6]; // (2,10,720)

  float* out = (float*)d_out;
  float* o_labels  = out;                                 // 16800
  float* o_bboxes  = o_labels + BS*NA;                    // 67200
  float* o_scores  = o_bboxes + BS*NA*4;                  // 1344000
  float* o_maskpos = o_scores + (size_t)BS*NA*NC;         // 168000
  float* o_gtidx   = o_maskpos + BS*NM*NA;                // 16800
  float* o_gtdist  = o_gtidx + BS*NA;                     // 6048000
  float* o_cent    = o_gtdist + (size_t)BS*NM*NA*NBIN;    // 168000
  float* o_fg      = o_cent + BS*NM*NA;                   // 16800

  float* wf      = (float*)d_ws;
  float* w_align = wf + 16;
  float* w_ovl   = w_align + BS*NM*NA;
  float* w_mask  = w_ovl + BS*NM*NA;
  float* w_pa    = w_mask + BS*NM*NA;
  float* w_po    = w_pa + BS*NM;

  k_zero<<<2048, 256, 0, stream>>>(out, wf);
  k_dist<<<4096, 256, 0, stream>>>(pds, pdb, anc, gl, gtb, mgt, coor, out, wf);
  k_topk<<<BS*NM, 256, 0, stream>>>(gtb, mgt, w_align, w_mask);
  k_final<<<(BS*NA+255)/256, 256, 0, stream>>>(w_align, w_ovl, w_mask, gl, gtb,
                                               o_labels, o_bboxes, o_maskpos, o_gtidx, o_fg,
                                               w_pa, w_po);
  k_fuse<<<NB_FIX + (BS*NA+255)/256, 256, 0, stream>>>(gtb, mgt, w_mask,
                                                       o_gtdist, o_cent,
                                                       w_align, w_pa, w_po,
                                                       o_labels, o_fg, o_gtidx, o_scores);
}